// Round 1
// baseline (395.111 us; speedup 1.0000x reference)
//
#include <hip/hip_runtime.h>
#include <stdint.h>

// MultiHeadedAttentionSANM: B=8,T=1024,F=1024,H=16,Dk=64,KERNEL=11
// Pipeline: cvt(hs,Wqkv,Wout)->bf16 | GEMM1 qkv | fsmn->d_out | flash-attn | GEMM2(+bias+fsmn)->d_out
// ws layout (bytes): hsb[0,16M) wqkvb[16M,22M) woutb[22M,24M) q[24M,40M) k[40M,56M) v[56M,72M) ctx[72M,88M)
// total ws needed = 92,274,688 bytes

typedef uint16_t u16;
typedef float f32x4 __attribute__((ext_vector_type(4)));
typedef __bf16 bf16x8 __attribute__((ext_vector_type(8)));

__device__ __forceinline__ u16 f2bf(float f) {
    union { float f; uint32_t u; } c; c.f = f;
    uint32_t u = c.u;
    return (u16)((u + 0x7fffu + ((u >> 16) & 1u)) >> 16);
}
__device__ __forceinline__ float bf2f(u16 h) {
    union { uint32_t u; float f; } c; c.u = ((uint32_t)h) << 16;
    return c.f;
}

// ---------------- fp32 -> bf16 convert ----------------
__global__ __launch_bounds__(256) void cvt_f32_bf16(const float* __restrict__ src,
                                                    u16* __restrict__ dst, int n) {
    int i = (blockIdx.x * 256 + threadIdx.x) * 4;
    if (i >= n) return;
    float4 v = *reinterpret_cast<const float4*>(src + i);
    ushort4 o;
    o.x = f2bf(v.x); o.y = f2bf(v.y); o.z = f2bf(v.z); o.w = f2bf(v.w);
    *reinterpret_cast<ushort4*>(dst + i) = o;
}

// ---------------- 128x128 bf16 MFMA GEMM, B given as [N,K] (B^T form) ----------------
// MODE 0: epilogue scatters qkv -> q(x0.125)/k/v in [B,H,T,64] bf16
// MODE 1: out[row,col] += acc + bias[col]   (out already holds fsmn memory)
template<int MODE>
__global__ __launch_bounds__(256) void gemm128(
    const u16* __restrict__ A, const u16* __restrict__ Bw, int M, int N, int K,
    int ntiles_n, const float* __restrict__ bias,
    u16* __restrict__ qo, u16* __restrict__ ko, u16* __restrict__ vo,
    float* __restrict__ out)
{
    __shared__ u16 As[128 * 32];
    __shared__ u16 Bs[128 * 32];
    const int t = threadIdx.x;
    const int lane = t & 63;
    const int wave = t >> 6;
    const int wr = wave >> 1, wc = wave & 1;
    const int lr = lane & 15, lq = lane >> 4;
    const int mt = blockIdx.x / ntiles_n;
    const int nt = blockIdx.x % ntiles_n;
    const int m0 = mt * 128, n0 = nt * 128;

    const u16* ag = A + (size_t)m0 * K;
    const u16* bg = Bw + (size_t)n0 * K;

    f32x4 acc[4][4];
#pragma unroll
    for (int i = 0; i < 4; ++i)
#pragma unroll
        for (int j = 0; j < 4; ++j) acc[i][j] = (f32x4){0.f, 0.f, 0.f, 0.f};

    for (int k0 = 0; k0 < K; k0 += 32) {
        // stage A,B tiles [128][32] bf16 via global_load_lds width 16
#pragma unroll
        for (int i = 0; i < 2; ++i) {
            int c = i * 256 + t;                 // chunk id: row=c>>2, colchunk=c&3
            const u16* gA = ag + (size_t)(c >> 2) * K + k0 + (c & 3) * 8;
            const u16* gB = bg + (size_t)(c >> 2) * K + k0 + (c & 3) * 8;
            __builtin_amdgcn_global_load_lds(
                (const __attribute__((address_space(1))) void*)gA,
                (__attribute__((address_space(3))) void*)(As + i * 2048 + wave * 512),
                16, 0, 0);
            __builtin_amdgcn_global_load_lds(
                (const __attribute__((address_space(1))) void*)gB,
                (__attribute__((address_space(3))) void*)(Bs + i * 2048 + wave * 512),
                16, 0, 0);
        }
        __syncthreads();
        bf16x8 af[4], bf[4];
#pragma unroll
        for (int m = 0; m < 4; ++m)
            af[m] = *reinterpret_cast<const bf16x8*>(As + (wr * 64 + m * 16 + lr) * 32 + lq * 8);
#pragma unroll
        for (int n = 0; n < 4; ++n)
            bf[n] = *reinterpret_cast<const bf16x8*>(Bs + (wc * 64 + n * 16 + lr) * 32 + lq * 8);
#pragma unroll
        for (int m = 0; m < 4; ++m)
#pragma unroll
            for (int n = 0; n < 4; ++n)
                acc[m][n] = __builtin_amdgcn_mfma_f32_16x16x32_bf16(af[m], bf[n], acc[m][n], 0, 0, 0);
        __syncthreads();
    }

    // epilogue: D layout col=lane&15, row=(lane>>4)*4+reg
#pragma unroll
    for (int m = 0; m < 4; ++m) {
        int row = m0 + wr * 64 + m * 16 + lq * 4;
#pragma unroll
        for (int n = 0; n < 4; ++n) {
            int col = n0 + wc * 64 + n * 16 + lr;
            float bv = bias[col];
#pragma unroll
            for (int r = 0; r < 4; ++r) {
                float val = acc[m][n][r] + bv;
                int rr = row + r;
                if (MODE == 0) {
                    int part = col >> 10;
                    int cc = col & 1023;
                    int h = cc >> 6, d = cc & 63;
                    int b = rr >> 10, tt = rr & 1023;
                    size_t o = (((size_t)(b * 16 + h) << 10) + tt) * 64 + d;
                    if (part == 0)      qo[o] = f2bf(val * 0.125f);  // fold Dk^-0.5
                    else if (part == 1) ko[o] = f2bf(val);
                    else                vo[o] = f2bf(val);
                } else {
                    size_t o = (size_t)rr * N + col;
                    out[o] += val;  // out holds fsmn memory
                }
            }
        }
    }
}

// ---------------- FSMN depthwise conv (writes fp32 into d_out) ----------------
__global__ __launch_bounds__(256) void fsmn_kernel(const u16* __restrict__ v,
                                                   const int* __restrict__ mask,
                                                   const float* __restrict__ kern,
                                                   float* __restrict__ out)
{
    int idx = blockIdx.x * 256 + threadIdx.x;     // [b,t,c]
    int c = idx & 1023;
    int tt = (idx >> 10) & 1023;
    int b = idx >> 20;
    float mf = (float)mask[(b << 10) + tt];
    int h = c >> 6, d = c & 63;
    const u16* vb = v + (((size_t)(b * 16 + h)) << 10) * 64 + d;
    const float* kc = kern + c * 11;
    float acc = 0.f;
#pragma unroll
    for (int j = 0; j < 11; ++j) {
        int ts = tt + j - 5;
        if (ts >= 0 && ts < 1024) {
            float mv = (float)mask[(b << 10) + ts];
            acc += kc[j] * (bf2f(vb[(size_t)ts * 64]) * mv);
        }
    }
    float vm = bf2f(vb[(size_t)tt * 64]) * mf;
    out[idx] = (acc + vm) * mf;
}

// ---------------- flash attention: block = (b,h,64 q-rows), 4 waves x 16 rows ----------------
__global__ __launch_bounds__(256) void attn_kernel(const u16* __restrict__ q,
                                                   const u16* __restrict__ k,
                                                   const u16* __restrict__ v,
                                                   const int* __restrict__ mask,
                                                   u16* __restrict__ ctx)
{
    __shared__ u16 Ks[64 * 64];   // [key_t][dk]  xor-swizzled 16B chunks
    __shared__ u16 Vt[64 * 64];   // [dk][key_t]  xor-swizzled
    __shared__ u16 Ps[64 * 64];   // [q_row][key_t] xor-swizzled
    const int t = threadIdx.x;
    const int lane = t & 63;
    const int w = t >> 6;
    const int lr = lane & 15, lq = lane >> 4;
    const int bid = blockIdx.x;
    const int qb = bid & 15;
    const int bh = bid >> 4;
    const int b = bh >> 4, h = bh & 15;
    const size_t base = (size_t)bh * 1024 * 64;
    const int* mrow = mask + (b << 10);

    // Q fragments direct from global (A operand: row=lane&15, k=8*(lane>>4)+e)
    bf16x8 qf[2];
    {
        const u16* qrow = q + base + (size_t)(qb * 64 + w * 16 + lr) * 64;
#pragma unroll
        for (int kk = 0; kk < 2; ++kk)
            qf[kk] = *reinterpret_cast<const bf16x8*>(qrow + kk * 32 + lq * 8);
    }

    f32x4 oacc[4];
    float mrun[4], lrun[4];
#pragma unroll
    for (int i = 0; i < 4; ++i) { oacc[i] = (f32x4){0, 0, 0, 0}; mrun[i] = -1e30f; lrun[i] = 0.f; }

    for (int kt = 0; kt < 16; ++kt) {
        __syncthreads();
        // stage K tile and V^T tile
#pragma unroll
        for (int i = 0; i < 2; ++i) {
            int c = i * 256 + t;
            int trow = c >> 3, g = c & 7;
            int4 kv = *reinterpret_cast<const int4*>(k + base + (size_t)(kt * 64 + trow) * 64 + g * 8);
            *reinterpret_cast<int4*>(Ks + trow * 64 + ((g ^ (trow & 7)) * 8)) = kv;
            int4 vv = *reinterpret_cast<const int4*>(v + base + (size_t)(kt * 64 + trow) * 64 + g * 8);
            u16 tmp[8];
            *reinterpret_cast<int4*>(tmp) = vv;
#pragma unroll
            for (int j = 0; j < 8; ++j) {
                int d = g * 8 + j;
                Vt[d * 64 + (((trow >> 3) ^ (d & 7)) * 8) + (trow & 7)] = tmp[j];
            }
        }
        __syncthreads();

        // S = Q K^T  (16 rows x 64 keys per wave)
        f32x4 s[4];
#pragma unroll
        for (int nt = 0; nt < 4; ++nt) {
            s[nt] = (f32x4){0, 0, 0, 0};
#pragma unroll
            for (int kk = 0; kk < 2; ++kk) {
                int row = nt * 16 + lr;
                bf16x8 kf = *reinterpret_cast<const bf16x8*>(Ks + row * 64 + (((kk * 4 + lq) ^ (row & 7)) * 8));
                s[nt] = __builtin_amdgcn_mfma_f32_16x16x32_bf16(qf[kk], kf, s[nt], 0, 0, 0);
            }
        }
        // key mask: whole f32x4 of a lane shares one column
#pragma unroll
        for (int nt = 0; nt < 4; ++nt) {
            int kcol = kt * 64 + nt * 16 + lr;
            if (mrow[kcol] == 0) s[nt] = (f32x4){-1e30f, -1e30f, -1e30f, -1e30f};
        }
        // online softmax (row r lives in reg r of the lq quarter-group; 16-lane reduce)
        float alpha[4], mnew[4];
#pragma unroll
        for (int r = 0; r < 4; ++r) {
            float mx = fmaxf(fmaxf(s[0][r], s[1][r]), fmaxf(s[2][r], s[3][r]));
#pragma unroll
            for (int off = 8; off >= 1; off >>= 1) mx = fmaxf(mx, __shfl_xor(mx, off, 64));
            float mn = fmaxf(mrun[r], mx);
            alpha[r] = __expf(mrun[r] - mn);
            mnew[r] = mn;
        }
        float rsum[4] = {0, 0, 0, 0};
        int prow0 = w * 16 + lq * 4;
#pragma unroll
        for (int nt = 0; nt < 4; ++nt) {
            int col = nt * 16 + lr;
#pragma unroll
            for (int r = 0; r < 4; ++r) {
                float p = __expf(s[nt][r] - mnew[r]);
                rsum[r] += p;
                int prow = prow0 + r;
                Ps[prow * 64 + (((col >> 3) ^ (prow & 7)) * 8) + (col & 7)] = f2bf(p);
            }
        }
#pragma unroll
        for (int r = 0; r < 4; ++r) {
            float sum = rsum[r];
#pragma unroll
            for (int off = 8; off >= 1; off >>= 1) sum += __shfl_xor(sum, off, 64);
            lrun[r] = lrun[r] * alpha[r] + sum;
            mrun[r] = mnew[r];
        }
#pragma unroll
        for (int dt = 0; dt < 4; ++dt) {
            f32x4 o = oacc[dt];
            o[0] *= alpha[0]; o[1] *= alpha[1]; o[2] *= alpha[2]; o[3] *= alpha[3];
            oacc[dt] = o;
        }
        __syncthreads();
        // O += P V   (A=P[16,64], B=V[64k,64d] via Vt)
#pragma unroll
        for (int dt = 0; dt < 4; ++dt) {
#pragma unroll
            for (int kk = 0; kk < 2; ++kk) {
                int prow = w * 16 + lr;
                bf16x8 pf = *reinterpret_cast<const bf16x8*>(Ps + prow * 64 + (((kk * 4 + lq) ^ (prow & 7)) * 8));
                int vrow = dt * 16 + lr;
                bf16x8 vf = *reinterpret_cast<const bf16x8*>(Vt + vrow * 64 + (((kk * 4 + lq) ^ (vrow & 7)) * 8));
                oacc[dt] = __builtin_amdgcn_mfma_f32_16x16x32_bf16(pf, vf, oacc[dt], 0, 0, 0);
            }
        }
    }

    // write ctx [B,T,1024] bf16
    const int trow0 = qb * 64 + w * 16 + lq * 4;
#pragma unroll
    for (int dt = 0; dt < 4; ++dt) {
#pragma unroll
        for (int r = 0; r < 4; ++r) {
            float val = oacc[dt][r] / lrun[r];
            size_t o = ((size_t)(b << 10) + trow0 + r) * 1024 + h * 64 + dt * 16 + lr;
            ctx[o] = f2bf(val);
        }
    }
}

extern "C" void kernel_launch(void* const* d_in, const int* in_sizes, int n_in,
                              void* d_out, int out_size, void* d_ws, size_t ws_size,
                              hipStream_t stream)
{
    (void)in_sizes; (void)n_in; (void)out_size; (void)ws_size;
    const float* hs   = (const float*)d_in[0];
    const int*   mask = (const int*)d_in[1];
    const float* Wqkv = (const float*)d_in[2];
    const float* bqkv = (const float*)d_in[3];
    const float* Wout = (const float*)d_in[4];
    const float* bout = (const float*)d_in[5];
    const float* fk   = (const float*)d_in[6];
    float* out = (float*)d_out;

    char* ws = (char*)d_ws;
    u16* hsb   = (u16*)(ws);                 // 8,388,608 elems
    u16* wqkvb = (u16*)(ws + 16777216);      // 3,145,728
    u16* woutb = (u16*)(ws + 23068672);      // 1,048,576
    u16* qb    = (u16*)(ws + 25165824);      // 8,388,608  [B,H,T,64]
    u16* kb    = (u16*)(ws + 41943040);
    u16* vb    = (u16*)(ws + 58720256);
    u16* ctxb  = (u16*)(ws + 75497472);      // [B,T,1024]

    cvt_f32_bf16<<<8192, 256, 0, stream>>>(hs,   hsb,   8388608);
    cvt_f32_bf16<<<3072, 256, 0, stream>>>(Wqkv, wqkvb, 3145728);
    cvt_f32_bf16<<<1024, 256, 0, stream>>>(Wout, woutb, 1048576);

    gemm128<0><<<64 * 24, 256, 0, stream>>>(hsb, wqkvb, 8192, 3072, 1024, 24,
                                            bqkv, qb, kb, vb, nullptr);
    fsmn_kernel<<<32768, 256, 0, stream>>>(vb, mask, fk, out);
    attn_kernel<<<2048, 256, 0, stream>>>(qb, kb, vb, mask, ctxb);
    gemm128<1><<<64 * 8, 256, 0, stream>>>(ctxb, woutb, 8192, 1024, 1024, 8,
                                           bout, nullptr, nullptr, nullptr, out);
}